// Round 2
// baseline (480.114 us; speedup 1.0000x reference)
//
#include <hip/hip_runtime.h>
#include <hip/hip_bf16.h>

// SAGEConv: out = x @ W_self^T + b_self + segsum(x[col]*w, row) @ W_neigh^T + b_neigh
// N=100000, E=1600000, C=64. ALL float tensors fp32 on device (per reference);
// edge_index int32 [2*E] (row=dst first E, col=src second E); output fp32 [N,64].

#define C 64

typedef __attribute__((ext_vector_type(8))) short bf16x8;   // MFMA A/B frag (4 VGPR)
typedef __attribute__((ext_vector_type(4))) float f32x4;    // MFMA C/D frag

// ---------------------------------------------------------------------------
// Kernel 1: scatter-add  agg[dst,c] += x[src,c] * w[e]   (fp32 atomics)
// One wave handles 64 edges per batch: coalesced metadata load, broadcast via
// shfl; lane = channel -> one 256B coalesced gather + one coalesced atomic
// row per edge. atomicAdd on global is device-scope (G12).
// ---------------------------------------------------------------------------
__global__ __launch_bounds__(256) void scatter_kernel(
        const float* __restrict__ x,
        const int* __restrict__ ei,          // [2*E]: ei[e]=dst(row), ei[E+e]=src(col)
        const float* __restrict__ ew,
        float* __restrict__ agg, int E) {
    const int lane = threadIdx.x & 63;
    const int wid  = (blockIdx.x * blockDim.x + threadIdx.x) >> 6;
    const int nw   = (gridDim.x * blockDim.x) >> 6;

    for (int base = wid * 64; base < E; base += nw * 64) {
        const int e = base + lane;
        int dst = 0, src = 0; float w = 0.f;
        if (e < E) {
            dst = ei[e];
            src = ei[E + e];
            w   = ew[e];
        }
        const int cnt = min(64, E - base);
        for (int j = 0; j < cnt; ++j) {
            const int   d  = __shfl(dst, j);
            const int   s  = __shfl(src, j);
            const float wj = __shfl(w, j);
            const float xv = x[s * C + lane];
            atomicAdd(&agg[d * C + lane], xv * wj);
        }
    }
}

// ---------------------------------------------------------------------------
// Kernel 2: fused projection as a K=128 bf16 MFMA GEMM.
// out[m,o] = sum_c x[m,c]*Ws[o,c] + agg[m,c]*Wn[o,c] + bs[o] + bn[o]
// A = [x | agg] (fp32 -> bf16 in regs). B[k][n] layout: n=lane&15, k=quad*8+j,
// and B[c][o] = W[o][c] -> each lane's B frag is 8 CONSECUTIVE elements of one
// W row: no transpose, no LDS. One wave per 16-node tile; W fully in VGPRs.
// C/D layout: col=lane&15, row=quad*4+r  [m89-verified].
// ---------------------------------------------------------------------------
__device__ inline bf16x8 cvt8(const float* __restrict__ p) {
    f32x4 lo = *(const f32x4*)p;
    f32x4 hi = *(const f32x4*)(p + 4);
    union { bf16x8 v; __hip_bfloat16 e[8]; } u;
#pragma unroll
    for (int j = 0; j < 4; ++j) u.e[j]     = __float2bfloat16(lo[j]);
#pragma unroll
    for (int j = 0; j < 4; ++j) u.e[4 + j] = __float2bfloat16(hi[j]);
    return u.v;
}

__global__ __launch_bounds__(256) void proj_kernel(
        const float* __restrict__ x,
        const float* __restrict__ agg,
        const float* __restrict__ Ws,
        const float* __restrict__ bs,
        const float* __restrict__ Wn,
        const float* __restrict__ bn,
        float* __restrict__ out, int N) {
    const int lane = threadIdx.x & 63;
    const int wid  = (blockIdx.x * blockDim.x + threadIdx.x) >> 6;
    const int l15  = lane & 15;
    const int quad = lane >> 4;
    const int nTiles = N >> 4;            // 100000/16 = 6250 exact
    if (wid >= nTiles) return;
    const int m0 = wid << 4;

    // B fragments: [o-tile][k-half], contiguous row-slices of W, cvt to bf16.
    bf16x8 bsf[4][2], bnf[4][2];
#pragma unroll
    for (int t = 0; t < 4; ++t) {
        const int o = t * 16 + l15;
#pragma unroll
        for (int h = 0; h < 2; ++h) {
            bsf[t][h] = cvt8(Ws + o * C + h * 32 + quad * 8);
            bnf[t][h] = cvt8(Wn + o * C + h * 32 + quad * 8);
        }
    }

    // A fragments: A[m=l15][k=quad*8+j]; k<64 from x, k>=64 from agg.
    const int m = m0 + l15;
    bf16x8 ax[2], ag[2];
#pragma unroll
    for (int h = 0; h < 2; ++h) {
        ax[h] = cvt8(x   + m * C + h * 32 + quad * 8);
        ag[h] = cvt8(agg + m * C + h * 32 + quad * 8);
    }

#pragma unroll
    for (int t = 0; t < 4; ++t) {
        f32x4 acc = {0.f, 0.f, 0.f, 0.f};
        acc = __builtin_amdgcn_mfma_f32_16x16x32_bf16(ax[0], bsf[t][0], acc, 0, 0, 0);
        acc = __builtin_amdgcn_mfma_f32_16x16x32_bf16(ax[1], bsf[t][1], acc, 0, 0, 0);
        acc = __builtin_amdgcn_mfma_f32_16x16x32_bf16(ag[0], bnf[t][0], acc, 0, 0, 0);
        acc = __builtin_amdgcn_mfma_f32_16x16x32_bf16(ag[1], bnf[t][1], acc, 0, 0, 0);

        const int o = t * 16 + l15;
        const float bias = bs[o] + bn[o];
#pragma unroll
        for (int r = 0; r < 4; ++r)
            out[(m0 + quad * 4 + r) * C + o] = acc[r] + bias;
    }
}

extern "C" void kernel_launch(void* const* d_in, const int* in_sizes, int n_in,
                              void* d_out, int out_size, void* d_ws, size_t ws_size,
                              hipStream_t stream) {
    const float* x  = (const float*)d_in[0];
    const int*   ei = (const int*)d_in[1];
    const float* ew = (const float*)d_in[2];
    const float* Ws = (const float*)d_in[3];
    const float* bs = (const float*)d_in[4];
    const float* Wn = (const float*)d_in[5];
    const float* bn = (const float*)d_in[6];

    const int N = in_sizes[0] / C;   // 100000
    const int E = in_sizes[2];       // 1600000

    float* agg = (float*)d_ws;       // N*C fp32 = 25.6 MB scratch

    hipMemsetAsync(agg, 0, (size_t)N * C * sizeof(float), stream);

    scatter_kernel<<<2048, 256, 0, stream>>>(x, ei, ew, agg, E);

    const int nTiles = N / 16;                 // 6250 waves
    const int blocks = (nTiles + 3) / 4;       // 4 waves / block
    proj_kernel<<<blocks, 256, 0, stream>>>(x, agg, Ws, bs, Wn, bn,
                                            (float*)d_out, N);
}

// Round 3
// 385.175 us; speedup vs baseline: 1.2465x; 1.2465x over previous
//
#include <hip/hip_runtime.h>
#include <hip/hip_bf16.h>

// SAGEConv: out = x @ W_self^T + b_self + segsum(x[col]*w, row) @ W_neigh^T + b_neigh
// N=100000, E=1600000, C=64. All float tensors fp32; edge_index int32 [2*E]
// (dst = first E, src = second E); output fp32 [N,64].
//
// R3 strategy: counting-sort edges by dst (hist + scan + bin), then gather-based
// per-node aggregation in registers (NO fp32 atomics on agg — R2 showed 102.4M
// atomics write through to HBM: WRITE_SIZE 400MB, 357us). x gathered as bf16
// (128B/edge instead of 256B). Projection = K=128 bf16 MFMA GEMM (unchanged).

#define C 64

typedef __attribute__((ext_vector_type(8))) short bf16x8;
typedef __attribute__((ext_vector_type(4))) float f32x4;

__device__ inline unsigned short f2bf(float f) {
    union { __hip_bfloat16 h; unsigned short u; } c;
    c.h = __float2bfloat16(f);
    return c.u;
}

// --------------------------------------------------------------------------
// prep: histogram of dst + convert x to bf16 (row-major N x 64).
// --------------------------------------------------------------------------
__global__ __launch_bounds__(256) void prep_kernel(
        const int* __restrict__ ei, int* __restrict__ cnt, int E,
        const float* __restrict__ x, unsigned short* __restrict__ xb, int n4) {
    const int tid = blockIdx.x * blockDim.x + threadIdx.x;
    const int stride = gridDim.x * blockDim.x;
    for (int e = tid; e < E; e += stride)
        atomicAdd(&cnt[ei[e]], 1);
    const float4* x4 = (const float4*)x;
    ushort4* xb4 = (ushort4*)xb;
    for (int i = tid; i < n4; i += stride) {
        float4 v = x4[i];
        ushort4 o;
        o.x = f2bf(v.x); o.y = f2bf(v.y); o.z = f2bf(v.z); o.w = f2bf(v.w);
        xb4[i] = o;
    }
}

// --------------------------------------------------------------------------
// 3-pass exclusive scan over cnt[N] -> offs[N] (+ offs[N]=E), cursors copy.
// CHUNK=1024 (256 thr x 4), block sums scanned by a single 256-thread block.
// --------------------------------------------------------------------------
__global__ __launch_bounds__(256) void scan1_kernel(
        const int* __restrict__ cnt, int* __restrict__ offs,
        int* __restrict__ bsum, int N) {
    __shared__ int sdata[256];
    const int t = threadIdx.x;
    const int idx = blockIdx.x * 1024 + t * 4;
    int v[4];
#pragma unroll
    for (int i = 0; i < 4; ++i) v[i] = (idx + i < N) ? cnt[idx + i] : 0;
    sdata[t] = v[0] + v[1] + v[2] + v[3];
    __syncthreads();
    for (int off = 1; off < 256; off <<= 1) {
        int val = 0;
        if (t >= off) val = sdata[t - off];
        __syncthreads();
        if (t >= off) sdata[t] += val;
        __syncthreads();
    }
    int run = (t > 0) ? sdata[t - 1] : 0;
#pragma unroll
    for (int i = 0; i < 4; ++i) {
        if (idx + i < N) offs[idx + i] = run;
        run += v[i];
    }
    if (t == 255) bsum[blockIdx.x] = sdata[255];
}

__global__ __launch_bounds__(256) void scan2_kernel(int* __restrict__ bsum, int NB) {
    __shared__ int sdata[256];
    const int t = threadIdx.x;
    sdata[t] = (t < NB) ? bsum[t] : 0;
    __syncthreads();
    for (int off = 1; off < 256; off <<= 1) {
        int val = 0;
        if (t >= off) val = sdata[t - off];
        __syncthreads();
        if (t >= off) sdata[t] += val;
        __syncthreads();
    }
    if (t < NB) bsum[t] = (t > 0) ? sdata[t - 1] : 0;
}

__global__ __launch_bounds__(256) void scan3_kernel(
        int* __restrict__ offs, int* __restrict__ cursors,
        const int* __restrict__ bsum, int N, int E) {
    const int t = threadIdx.x;
    const int idx = blockIdx.x * 1024 + t * 4;
    const int add = bsum[blockIdx.x];
#pragma unroll
    for (int i = 0; i < 4; ++i) {
        if (idx + i < N) {
            int v = offs[idx + i] + add;
            offs[idx + i] = v;
            cursors[idx + i] = v;
        }
    }
    if (blockIdx.x == 0 && t == 0) offs[N] = E;
}

// --------------------------------------------------------------------------
// binning: place (src, w) of each edge into its dst segment.
// --------------------------------------------------------------------------
__global__ __launch_bounds__(256) void bin_kernel(
        const int* __restrict__ ei, const float* __restrict__ ew,
        int* __restrict__ cursors, int2* __restrict__ sorted, int E) {
    const int tid = blockIdx.x * blockDim.x + threadIdx.x;
    const int stride = gridDim.x * blockDim.x;
    for (int e = tid; e < E; e += stride) {
        const int d = ei[e];
        const int s = ei[E + e];
        const float w = ew[e];
        const int pos = atomicAdd(&cursors[d], 1);
        sorted[pos] = make_int2(s, __float_as_int(w));
    }
}

// --------------------------------------------------------------------------
// aggregate: one wave per dst node. Two edges in flight (one per half-wave);
// each lane holds a bf16x2 channel pair (cl = lane&31 -> channels 2cl,2cl+1).
// Combine halves with shfl_xor(32); lanes 0-31 store the fp32 row (float2).
// --------------------------------------------------------------------------
__global__ __launch_bounds__(256) void agg_kernel(
        const unsigned short* __restrict__ xb,
        const int2* __restrict__ sorted,
        const int* __restrict__ offs,
        float* __restrict__ agg, int N) {
    const int lane = threadIdx.x & 63;
    const int d = (blockIdx.x * blockDim.x + threadIdx.x) >> 6;
    if (d >= N) return;
    const int half = lane >> 5;
    const int cl = lane & 31;
    const int beg = offs[d];
    const int end = offs[d + 1];

    float ax = 0.f, ay = 0.f;
    for (int b = beg; b < end; b += 64) {
        int2 meta = make_int2(0, 0);           // w = 0 -> safe no-op
        if (b + lane < end) meta = sorted[b + lane];
        const int cnt = min(64, end - b);
        for (int j = 0; j < cnt; j += 2) {
            const int jj = j + half;           // lanes beyond cnt carry w=0
            const int s = __shfl(meta.x, jj);
            const float w = __int_as_float(__shfl(meta.y, jj));
            const unsigned u = *(const unsigned*)(xb + (size_t)s * C + 2 * cl);
            const float xlo = __int_as_float((int)(u << 16));
            const float xhi = __int_as_float((int)(u & 0xffff0000u));
            ax += w * xlo;
            ay += w * xhi;
        }
    }
    ax += __shfl_xor(ax, 32);
    ay += __shfl_xor(ay, 32);
    if (half == 0) {
        float2 o = make_float2(ax, ay);
        *(float2*)(agg + (size_t)d * C + 2 * cl) = o;
    }
}

// --------------------------------------------------------------------------
// R2 fallback scatter (used only if ws_size is too small for the CSR path).
// --------------------------------------------------------------------------
__global__ __launch_bounds__(256) void scatter_kernel(
        const float* __restrict__ x, const int* __restrict__ ei,
        const float* __restrict__ ew, float* __restrict__ agg, int E) {
    const int lane = threadIdx.x & 63;
    const int wid = (blockIdx.x * blockDim.x + threadIdx.x) >> 6;
    const int nw = (gridDim.x * blockDim.x) >> 6;
    for (int base = wid * 64; base < E; base += nw * 64) {
        const int e = base + lane;
        int dst = 0, src = 0; float w = 0.f;
        if (e < E) { dst = ei[e]; src = ei[E + e]; w = ew[e]; }
        const int cnt = min(64, E - base);
        for (int j = 0; j < cnt; ++j) {
            const int d = __shfl(dst, j);
            const int s = __shfl(src, j);
            const float wj = __shfl(w, j);
            atomicAdd(&agg[d * C + lane], x[s * C + lane] * wj);
        }
    }
}

// --------------------------------------------------------------------------
// proj: out = [x | agg] @ [Ws | Wn]^T + bs + bn as K=128 bf16 MFMA GEMM.
// B-frag = contiguous W row slice (no transpose). C/D: col=lane&15, row=quad*4+r.
// --------------------------------------------------------------------------
__device__ inline bf16x8 cvt8(const float* __restrict__ p) {
    f32x4 lo = *(const f32x4*)p;
    f32x4 hi = *(const f32x4*)(p + 4);
    union { bf16x8 v; __hip_bfloat16 e[8]; } u;
#pragma unroll
    for (int j = 0; j < 4; ++j) u.e[j] = __float2bfloat16(lo[j]);
#pragma unroll
    for (int j = 0; j < 4; ++j) u.e[4 + j] = __float2bfloat16(hi[j]);
    return u.v;
}

__global__ __launch_bounds__(256) void proj_kernel(
        const float* __restrict__ x, const float* __restrict__ agg,
        const float* __restrict__ Ws, const float* __restrict__ bs,
        const float* __restrict__ Wn, const float* __restrict__ bn,
        float* __restrict__ out, int N) {
    const int lane = threadIdx.x & 63;
    const int wid = (blockIdx.x * blockDim.x + threadIdx.x) >> 6;
    const int l15 = lane & 15;
    const int quad = lane >> 4;
    const int nTiles = N >> 4;
    if (wid >= nTiles) return;
    const int m0 = wid << 4;

    bf16x8 bsf[4][2], bnf[4][2];
#pragma unroll
    for (int t = 0; t < 4; ++t) {
        const int o = t * 16 + l15;
#pragma unroll
        for (int h = 0; h < 2; ++h) {
            bsf[t][h] = cvt8(Ws + o * C + h * 32 + quad * 8);
            bnf[t][h] = cvt8(Wn + o * C + h * 32 + quad * 8);
        }
    }

    const int m = m0 + l15;
    bf16x8 ax[2], ag[2];
#pragma unroll
    for (int h = 0; h < 2; ++h) {
        ax[h] = cvt8(x + m * C + h * 32 + quad * 8);
        ag[h] = cvt8(agg + m * C + h * 32 + quad * 8);
    }

#pragma unroll
    for (int t = 0; t < 4; ++t) {
        f32x4 acc = {0.f, 0.f, 0.f, 0.f};
        acc = __builtin_amdgcn_mfma_f32_16x16x32_bf16(ax[0], bsf[t][0], acc, 0, 0, 0);
        acc = __builtin_amdgcn_mfma_f32_16x16x32_bf16(ax[1], bsf[t][1], acc, 0, 0, 0);
        acc = __builtin_amdgcn_mfma_f32_16x16x32_bf16(ag[0], bnf[t][0], acc, 0, 0, 0);
        acc = __builtin_amdgcn_mfma_f32_16x16x32_bf16(ag[1], bnf[t][1], acc, 0, 0, 0);
        const int o = t * 16 + l15;
        const float bias = bs[o] + bn[o];
#pragma unroll
        for (int r = 0; r < 4; ++r)
            out[(m0 + quad * 4 + r) * C + o] = acc[r] + bias;
    }
}

extern "C" void kernel_launch(void* const* d_in, const int* in_sizes, int n_in,
                              void* d_out, int out_size, void* d_ws, size_t ws_size,
                              hipStream_t stream) {
    const float* x  = (const float*)d_in[0];
    const int*   ei = (const int*)d_in[1];
    const float* ew = (const float*)d_in[2];
    const float* Ws = (const float*)d_in[3];
    const float* bs = (const float*)d_in[4];
    const float* Wn = (const float*)d_in[5];
    const float* bn = (const float*)d_in[6];

    const int N = in_sizes[0] / C;   // 100000
    const int E = in_sizes[2];       // 1600000

    // Workspace layout
    char* p = (char*)d_ws;
    float* agg = (float*)p;                 p += (size_t)N * C * sizeof(float);   // 25.6MB
    unsigned short* xb = (unsigned short*)p; p += (size_t)N * C * sizeof(short);  // 12.8MB
    int2* sorted = (int2*)p;                p += (size_t)E * sizeof(int2);        // 12.8MB
    int* cnt = (int*)p;                     p += (size_t)N * sizeof(int);
    int* offs = (int*)p;                    p += (size_t)(N + 1) * sizeof(int);
    int* cursors = (int*)p;                 p += (size_t)N * sizeof(int);
    int* bsum = (int*)p;                    p += 4096;
    const size_t needed = (size_t)(p - (char*)d_ws);

    const int nTiles = N / 16;
    const int projBlocks = (nTiles + 3) / 4;

    if (needed <= ws_size) {
        const int NB = (N + 1023) / 1024;   // 98 (<=256 required by scan2)
        hipMemsetAsync(cnt, 0, (size_t)N * sizeof(int), stream);
        prep_kernel<<<1024, 256, 0, stream>>>(ei, cnt, E, x, xb, N * C / 4);
        scan1_kernel<<<NB, 256, 0, stream>>>(cnt, offs, bsum, N);
        scan2_kernel<<<1, 256, 0, stream>>>(bsum, NB);
        scan3_kernel<<<NB, 256, 0, stream>>>(offs, cursors, bsum, N, E);
        bin_kernel<<<1024, 256, 0, stream>>>(ei, ew, cursors, sorted, E);
        agg_kernel<<<(N + 3) / 4, 256, 0, stream>>>(xb, sorted, offs, agg, N);
    } else {
        // Fallback: R2 atomic path (agg fits in any ws that held R2).
        hipMemsetAsync(agg, 0, (size_t)N * C * sizeof(float), stream);
        scatter_kernel<<<2048, 256, 0, stream>>>(x, ei, ew, agg, E);
    }

    proj_kernel<<<projBlocks, 256, 0, stream>>>(x, agg, Ws, bs, Wn, bn,
                                                (float*)d_out, N);
}

// Round 4
// 378.033 us; speedup vs baseline: 1.2700x; 1.0189x over previous
//
#include <hip/hip_runtime.h>
#include <hip/hip_bf16.h>

// SAGEConv: out = x @ W_self^T + b_self + segsum(x[col]*w, row) @ W_neigh^T + b_neigh
// N=100000, E=1600000, C=64. All float tensors fp32; edge_index int32 [2*E]
// (dst = first E, src = second E); output fp32 [N,64].
//
// R4: R3's bin_kernel was LATENCY-bound (VALU 0.3%, HBM 11%, occ 39%): per-thread
// loop serialized atomic->store chains. Fix: one thread per edge, no loops, max MLP.

#define C 64

typedef __attribute__((ext_vector_type(8))) short bf16x8;
typedef __attribute__((ext_vector_type(4))) float f32x4;

__device__ inline unsigned short f2bf(float f) {
    union { __hip_bfloat16 h; unsigned short u; } c;
    c.h = __float2bfloat16(f);
    return c.u;
}

// --------------------------------------------------------------------------
// prep: histogram of dst + convert x to bf16. One thread per edge AND per
// float4 of x (E == N*C/4 == 1.6M, same grid covers both).
// --------------------------------------------------------------------------
__global__ __launch_bounds__(256) void prep_kernel(
        const int* __restrict__ ei, int* __restrict__ cnt, int E,
        const float* __restrict__ x, unsigned short* __restrict__ xb, int n4) {
    const int tid = blockIdx.x * blockDim.x + threadIdx.x;
    if (tid < E) atomicAdd(&cnt[ei[tid]], 1);
    if (tid < n4) {
        float4 v = ((const float4*)x)[tid];
        ushort4 o;
        o.x = f2bf(v.x); o.y = f2bf(v.y); o.z = f2bf(v.z); o.w = f2bf(v.w);
        ((ushort4*)xb)[tid] = o;
    }
}

// --------------------------------------------------------------------------
// 3-pass exclusive scan over cnt[N] -> offs[N] (+ offs[N]=E), cursors copy.
// --------------------------------------------------------------------------
__global__ __launch_bounds__(256) void scan1_kernel(
        const int* __restrict__ cnt, int* __restrict__ offs,
        int* __restrict__ bsum, int N) {
    __shared__ int sdata[256];
    const int t = threadIdx.x;
    const int idx = blockIdx.x * 1024 + t * 4;
    int v[4];
#pragma unroll
    for (int i = 0; i < 4; ++i) v[i] = (idx + i < N) ? cnt[idx + i] : 0;
    sdata[t] = v[0] + v[1] + v[2] + v[3];
    __syncthreads();
    for (int off = 1; off < 256; off <<= 1) {
        int val = 0;
        if (t >= off) val = sdata[t - off];
        __syncthreads();
        if (t >= off) sdata[t] += val;
        __syncthreads();
    }
    int run = (t > 0) ? sdata[t - 1] : 0;
#pragma unroll
    for (int i = 0; i < 4; ++i) {
        if (idx + i < N) offs[idx + i] = run;
        run += v[i];
    }
    if (t == 255) bsum[blockIdx.x] = sdata[255];
}

__global__ __launch_bounds__(256) void scan2_kernel(int* __restrict__ bsum, int NB) {
    __shared__ int sdata[256];
    const int t = threadIdx.x;
    sdata[t] = (t < NB) ? bsum[t] : 0;
    __syncthreads();
    for (int off = 1; off < 256; off <<= 1) {
        int val = 0;
        if (t >= off) val = sdata[t - off];
        __syncthreads();
        if (t >= off) sdata[t] += val;
        __syncthreads();
    }
    if (t < NB) bsum[t] = (t > 0) ? sdata[t - 1] : 0;
}

__global__ __launch_bounds__(256) void scan3_kernel(
        int* __restrict__ offs, int* __restrict__ cursors,
        const int* __restrict__ bsum, int N, int E) {
    const int t = threadIdx.x;
    const int idx = blockIdx.x * 1024 + t * 4;
    const int add = bsum[blockIdx.x];
#pragma unroll
    for (int i = 0; i < 4; ++i) {
        if (idx + i < N) {
            int v = offs[idx + i] + add;
            offs[idx + i] = v;
            cursors[idx + i] = v;
        }
    }
    if (blockIdx.x == 0 && t == 0) offs[N] = E;
}

// --------------------------------------------------------------------------
// binning: one thread per edge, no loop. Independent atomic+store per thread
// so L2 atomic latency overlaps across ~524K resident threads.
// --------------------------------------------------------------------------
__global__ __launch_bounds__(256) void bin_kernel(
        const int* __restrict__ ei, const float* __restrict__ ew,
        int* __restrict__ cursors, int2* __restrict__ sorted, int E) {
    const int e = blockIdx.x * blockDim.x + threadIdx.x;
    if (e >= E) return;
    const int d = ei[e];
    const int s = ei[E + e];
    const float w = ew[e];
    const int pos = atomicAdd(&cursors[d], 1);
    sorted[pos] = make_int2(s, __float_as_int(w));
}

// --------------------------------------------------------------------------
// aggregate: one wave per dst node; two edges in flight (one per half-wave);
// lane holds a bf16x2 channel pair. Register accumulate, one coalesced store.
// --------------------------------------------------------------------------
__global__ __launch_bounds__(256) void agg_kernel(
        const unsigned short* __restrict__ xb,
        const int2* __restrict__ sorted,
        const int* __restrict__ offs,
        float* __restrict__ agg, int N) {
    const int lane = threadIdx.x & 63;
    const int d = (blockIdx.x * blockDim.x + threadIdx.x) >> 6;
    if (d >= N) return;
    const int half = lane >> 5;
    const int cl = lane & 31;
    const int beg = offs[d];
    const int end = offs[d + 1];

    float ax = 0.f, ay = 0.f;
    for (int b = beg; b < end; b += 64) {
        int2 meta = make_int2(0, 0);           // w = 0 -> safe no-op
        if (b + lane < end) meta = sorted[b + lane];
        const int cnt = min(64, end - b);
        for (int j = 0; j < cnt; j += 2) {
            const int jj = j + half;
            const int s = __shfl(meta.x, jj);
            const float w = __int_as_float(__shfl(meta.y, jj));
            const unsigned u = *(const unsigned*)(xb + (size_t)s * C + 2 * cl);
            const float xlo = __int_as_float((int)(u << 16));
            const float xhi = __int_as_float((int)(u & 0xffff0000u));
            ax += w * xlo;
            ay += w * xhi;
        }
    }
    ax += __shfl_xor(ax, 32);
    ay += __shfl_xor(ay, 32);
    if (half == 0)
        *(float2*)(agg + (size_t)d * C + 2 * cl) = make_float2(ax, ay);
}

// --------------------------------------------------------------------------
// R2 fallback scatter (only if ws_size too small for the CSR path).
// --------------------------------------------------------------------------
__global__ __launch_bounds__(256) void scatter_kernel(
        const float* __restrict__ x, const int* __restrict__ ei,
        const float* __restrict__ ew, float* __restrict__ agg, int E) {
    const int lane = threadIdx.x & 63;
    const int wid = (blockIdx.x * blockDim.x + threadIdx.x) >> 6;
    const int nw = (gridDim.x * blockDim.x) >> 6;
    for (int base = wid * 64; base < E; base += nw * 64) {
        const int e = base + lane;
        int dst = 0, src = 0; float w = 0.f;
        if (e < E) { dst = ei[e]; src = ei[E + e]; w = ew[e]; }
        const int cnt = min(64, E - base);
        for (int j = 0; j < cnt; ++j) {
            const int d = __shfl(dst, j);
            const int s = __shfl(src, j);
            const float wj = __shfl(w, j);
            atomicAdd(&agg[d * C + lane], x[s * C + lane] * wj);
        }
    }
}

// --------------------------------------------------------------------------
// proj: out = [x | agg] @ [Ws | Wn]^T + bs + bn as K=128 bf16 MFMA GEMM.
// --------------------------------------------------------------------------
__device__ inline bf16x8 cvt8(const float* __restrict__ p) {
    f32x4 lo = *(const f32x4*)p;
    f32x4 hi = *(const f32x4*)(p + 4);
    union { bf16x8 v; __hip_bfloat16 e[8]; } u;
#pragma unroll
    for (int j = 0; j < 4; ++j) u.e[j] = __float2bfloat16(lo[j]);
#pragma unroll
    for (int j = 0; j < 4; ++j) u.e[4 + j] = __float2bfloat16(hi[j]);
    return u.v;
}

__global__ __launch_bounds__(256) void proj_kernel(
        const float* __restrict__ x, const float* __restrict__ agg,
        const float* __restrict__ Ws, const float* __restrict__ bs,
        const float* __restrict__ Wn, const float* __restrict__ bn,
        float* __restrict__ out, int N) {
    const int lane = threadIdx.x & 63;
    const int wid = (blockIdx.x * blockDim.x + threadIdx.x) >> 6;
    const int l15 = lane & 15;
    const int quad = lane >> 4;
    const int nTiles = N >> 4;
    if (wid >= nTiles) return;
    const int m0 = wid << 4;

    bf16x8 bsf[4][2], bnf[4][2];
#pragma unroll
    for (int t = 0; t < 4; ++t) {
        const int o = t * 16 + l15;
#pragma unroll
        for (int h = 0; h < 2; ++h) {
            bsf[t][h] = cvt8(Ws + o * C + h * 32 + quad * 8);
            bnf[t][h] = cvt8(Wn + o * C + h * 32 + quad * 8);
        }
    }

    const int m = m0 + l15;
    bf16x8 ax[2], ag[2];
#pragma unroll
    for (int h = 0; h < 2; ++h) {
        ax[h] = cvt8(x + m * C + h * 32 + quad * 8);
        ag[h] = cvt8(agg + m * C + h * 32 + quad * 8);
    }

#pragma unroll
    for (int t = 0; t < 4; ++t) {
        f32x4 acc = {0.f, 0.f, 0.f, 0.f};
        acc = __builtin_amdgcn_mfma_f32_16x16x32_bf16(ax[0], bsf[t][0], acc, 0, 0, 0);
        acc = __builtin_amdgcn_mfma_f32_16x16x32_bf16(ax[1], bsf[t][1], acc, 0, 0, 0);
        acc = __builtin_amdgcn_mfma_f32_16x16x32_bf16(ag[0], bnf[t][0], acc, 0, 0, 0);
        acc = __builtin_amdgcn_mfma_f32_16x16x32_bf16(ag[1], bnf[t][1], acc, 0, 0, 0);
        const int o = t * 16 + l15;
        const float bias = bs[o] + bn[o];
#pragma unroll
        for (int r = 0; r < 4; ++r)
            out[(m0 + quad * 4 + r) * C + o] = acc[r] + bias;
    }
}

extern "C" void kernel_launch(void* const* d_in, const int* in_sizes, int n_in,
                              void* d_out, int out_size, void* d_ws, size_t ws_size,
                              hipStream_t stream) {
    const float* x  = (const float*)d_in[0];
    const int*   ei = (const int*)d_in[1];
    const float* ew = (const float*)d_in[2];
    const float* Ws = (const float*)d_in[3];
    const float* bs = (const float*)d_in[4];
    const float* Wn = (const float*)d_in[5];
    const float* bn = (const float*)d_in[6];

    const int N = in_sizes[0] / C;   // 100000
    const int E = in_sizes[2];       // 1600000

    // Workspace layout
    char* p = (char*)d_ws;
    float* agg = (float*)p;                 p += (size_t)N * C * sizeof(float);   // 25.6MB
    unsigned short* xb = (unsigned short*)p; p += (size_t)N * C * sizeof(short);  // 12.8MB
    int2* sorted = (int2*)p;                p += (size_t)E * sizeof(int2);        // 12.8MB
    int* cnt = (int*)p;                     p += (size_t)N * sizeof(int);
    int* offs = (int*)p;                    p += (size_t)(N + 1) * sizeof(int);
    int* cursors = (int*)p;                 p += (size_t)N * sizeof(int);
    int* bsum = (int*)p;                    p += 4096;
    const size_t needed = (size_t)(p - (char*)d_ws);

    const int nTiles = N / 16;
    const int projBlocks = (nTiles + 3) / 4;

    if (needed <= ws_size) {
        const int NB = (N + 1023) / 1024;   // 98
        const int n4 = N * C / 4;           // 1.6M, == E here
        const int wide = max(E, n4);
        hipMemsetAsync(cnt, 0, (size_t)N * sizeof(int), stream);
        prep_kernel<<<(wide + 255) / 256, 256, 0, stream>>>(ei, cnt, E, x, xb, n4);
        scan1_kernel<<<NB, 256, 0, stream>>>(cnt, offs, bsum, N);
        scan2_kernel<<<1, 256, 0, stream>>>(bsum, NB);
        scan3_kernel<<<NB, 256, 0, stream>>>(offs, cursors, bsum, N, E);
        bin_kernel<<<(E + 255) / 256, 256, 0, stream>>>(ei, ew, cursors, sorted, E);
        agg_kernel<<<(N + 3) / 4, 256, 0, stream>>>(xb, sorted, offs, agg, N);
    } else {
        hipMemsetAsync(agg, 0, (size_t)N * C * sizeof(float), stream);
        scatter_kernel<<<2048, 256, 0, stream>>>(x, ei, ew, agg, E);
    }

    proj_kernel<<<projBlocks, 256, 0, stream>>>(x, agg, Ws, bs, Wn, bn,
                                                (float*)d_out, N);
}